// Round 13
// baseline (180.910 us; speedup 1.0000x reference)
//
#include <hip/hip_runtime.h>

#define NROWS 8192
#define NCENT 4096
#define DIM   256

typedef short bf16x8 __attribute__((ext_vector_type(8)));
typedef float f32x4  __attribute__((ext_vector_type(4)));

// fp32 -> bf16 round-to-nearest-even
__device__ inline unsigned short f2bf(float f) {
    unsigned u = __float_as_uint(f);
    return (unsigned short)((u + 0x7fffu + ((u >> 16) & 1u)) >> 16);
}

// ---------------------------------------------------------------------------
// FUSED single kernel: conversion + norms + GEMM + RBF epilogue.
// Eliminates the prep kernel (~11-12us HBM round-trip of 72MB), its launch
// gap, and all workspace use. Each 128x128-tile block register-stages fp32
// inputs directly: global float4 x2 -> f2bf x8 -> swizzled ds_write_b128,
// accumulating row norms in the same pass (block stages full K for its rows,
// so block-local norms are complete). Norms shared via 1KB LDS for epilogue.
//
// GEMM core: R6-proven 128x128 tile, BK=32, 4 waves (2x2), 4x4 MFMA frags,
// cross-iter LDS double-buffer, single __syncthreads per K-iter.
// LDS layout: row-major [row][32 bf16], 64B/row, 4 chunks of 16B; physical
// chunk p at row r holds logical chunk p^((r>>1)&3) -> frag ds_read_b128 is
// 2-way bank aliasing (free, m136). Write-side: lane writes PHYSICAL chunk
// (lane&3) with data of LOGICAL chunk c_l = (lane&3)^((r_in>>1)&3); since
// r = 32w+16h+r_in and (32w+16h)>>1 ≡ 0 mod 4, the row key reduces to r_in's.
// Epilogue: phi = w*exp(-sigma*max(d2,0)); 16-lane shfl reduce; atomicAdd.
// ---------------------------------------------------------------------------
#define BUFH (128 * 32)   // shorts per matrix per buffer (8 KB)

__global__ __launch_bounds__(256) void rbf_fused(const float* __restrict__ x,
                                                 const float* __restrict__ cent,
                                                 const float* __restrict__ w,
                                                 const float* __restrict__ sigp,
                                                 float* __restrict__ out) {
    __shared__ __align__(16) short As[2 * BUFH];   // 16 KB
    __shared__ __align__(16) short Bs[2 * BUFH];   // 16 KB
    __shared__ float nA[128];                      // row norms of A-tile
    __shared__ float nB[128];                      // row norms of B-tile

    const int t    = threadIdx.x;
    const int wave = t >> 6, lane = t & 63;
    const int m0   = blockIdx.y * 128;
    const int n0   = blockIdx.x * 128;
    const int wy   = wave >> 1, wx = wave & 1;
    const int lr   = lane & 15;       // frag m/n index
    const int g    = lane >> 4;       // frag k-group

    // ---- staging addressing: wave stages rows 32w..32w+31 (h=0,1 halves) ----
    const int r_in = lane >> 2;                        // 0..15 within 16-row group
    const int s4   = lane & 3;                         // physical chunk this lane writes
    const int c_l  = s4 ^ ((r_in >> 1) & 3);           // logical chunk this lane loads
    // global fp32 sources (advance by kk*32 floats)
    const float* gax[2];
    const float* gbx[2];
    #pragma unroll
    for (int h = 0; h < 2; ++h) {
        gax[h] = x    + (size_t)(m0 + 32 * wave + 16 * h + r_in) * DIM + c_l * 8;
        gbx[h] = cent + (size_t)(n0 + 32 * wave + 16 * h + r_in) * DIM + c_l * 8;
    }
    // LDS dests (shorts): row-local * 32 + physical chunk * 8
    short* la[2];
    short* lb[2];
    #pragma unroll
    for (int h = 0; h < 2; ++h) {
        la[h] = As + (32 * wave + 16 * h + r_in) * 32 + s4 * 8;
        lb[h] = Bs + (32 * wave + 16 * h + r_in) * 32 + s4 * 8;
    }

    float nrmA[2] = {0.f, 0.f}, nrmB[2] = {0.f, 0.f};

    // stage K-chunk kk into buffer buf, accumulating norms
#define STAGE(buf, kk) do {                                                                  \
        const int ko_ = (kk) * 32;                                                           \
        _Pragma("unroll")                                                                    \
        for (int h = 0; h < 2; ++h) {                                                        \
            f32x4 a0 = *(const f32x4*)(gax[h] + ko_);                                        \
            f32x4 a1 = *(const f32x4*)(gax[h] + ko_ + 4);                                    \
            f32x4 b0 = *(const f32x4*)(gbx[h] + ko_);                                        \
            f32x4 b1 = *(const f32x4*)(gbx[h] + ko_ + 4);                                    \
            nrmA[h] += a0[0]*a0[0]+a0[1]*a0[1]+a0[2]*a0[2]+a0[3]*a0[3]                       \
                     + a1[0]*a1[0]+a1[1]*a1[1]+a1[2]*a1[2]+a1[3]*a1[3];                      \
            nrmB[h] += b0[0]*b0[0]+b0[1]*b0[1]+b0[2]*b0[2]+b0[3]*b0[3]                       \
                     + b1[0]*b1[0]+b1[1]*b1[1]+b1[2]*b1[2]+b1[3]*b1[3];                      \
            union { unsigned short s[8]; int4 v; } ua, ub;                                   \
            ua.s[0]=f2bf(a0[0]); ua.s[1]=f2bf(a0[1]); ua.s[2]=f2bf(a0[2]); ua.s[3]=f2bf(a0[3]);\
            ua.s[4]=f2bf(a1[0]); ua.s[5]=f2bf(a1[1]); ua.s[6]=f2bf(a1[2]); ua.s[7]=f2bf(a1[3]);\
            ub.s[0]=f2bf(b0[0]); ub.s[1]=f2bf(b0[1]); ub.s[2]=f2bf(b0[2]); ub.s[3]=f2bf(b0[3]);\
            ub.s[4]=f2bf(b1[0]); ub.s[5]=f2bf(b1[1]); ub.s[6]=f2bf(b1[2]); ub.s[7]=f2bf(b1[3]);\
            *(int4*)(la[h] + (buf) * BUFH) = ua.v;                                           \
            *(int4*)(lb[h] + (buf) * BUFH) = ub.v;                                           \
        }                                                                                    \
    } while (0)

    // ---- fragment read offsets (shorts) ----
    int aoff[4], boff[4];
    #pragma unroll
    for (int i = 0; i < 4; ++i) {
        int r = 64 * wy + 16 * i + lr;
        aoff[i] = r * 32 + ((g ^ ((r >> 1) & 3)) * 8);
    }
    #pragma unroll
    for (int j = 0; j < 4; ++j) {
        int r = 64 * wx + 16 * j + lr;
        boff[j] = r * 32 + ((g ^ ((r >> 1) & 3)) * 8);
    }

    f32x4 acc[4][4];
    #pragma unroll
    for (int i = 0; i < 4; ++i)
        #pragma unroll
        for (int j = 0; j < 4; ++j) acc[i][j] = f32x4{0, 0, 0, 0};

    // ---- prologue: stage tile 0 ----
    STAGE(0, 0);
    __syncthreads();

    #pragma unroll
    for (int kk = 0; kk < DIM / 32; ++kk) {
        const int cur = kk & 1;
        if (kk < DIM / 32 - 1) STAGE(cur ^ 1, kk + 1);   // loads+cvt land under MFMA

        const short* Ab = As + cur * BUFH;
        const short* Bb = Bs + cur * BUFH;
        bf16x8 a[4], b[4];
        #pragma unroll
        for (int i = 0; i < 4; ++i) a[i] = *(const bf16x8*)(Ab + aoff[i]);
        #pragma unroll
        for (int j = 0; j < 4; ++j) b[j] = *(const bf16x8*)(Bb + boff[j]);
        #pragma unroll
        for (int i = 0; i < 4; ++i)
            #pragma unroll
            for (int j = 0; j < 4; ++j)
                acc[i][j] = __builtin_amdgcn_mfma_f32_16x16x32_bf16(a[i], b[j], acc[i][j], 0, 0, 0);

        __syncthreads();   // cur reads done before restage; next writes visible
    }
#undef STAGE

    // ---- finalize norms: reduce over the 4 chunk-lanes per row, post to LDS ----
    #pragma unroll
    for (int h = 0; h < 2; ++h) {
        nrmA[h] += __shfl_xor(nrmA[h], 1);
        nrmA[h] += __shfl_xor(nrmA[h], 2);
        nrmB[h] += __shfl_xor(nrmB[h], 1);
        nrmB[h] += __shfl_xor(nrmB[h], 2);
        if (s4 == 0) {
            nA[32 * wave + 16 * h + r_in] = nrmA[h];
            nB[32 * wave + 16 * h + r_in] = nrmB[h];
        }
    }
    __syncthreads();

    // ---- epilogue: phi = w*exp(-sigma*max(d2,0)); reduce 64 cols per row ----
    const float sigma = sigp[0];

    float c2v[4], wv[4];
    #pragma unroll
    for (int j = 0; j < 4; ++j) {
        int nl = 64 * wx + 16 * j + lr;       // local col in tile
        c2v[j] = nB[nl];
        wv[j]  = w[n0 + nl];
    }

    #pragma unroll
    for (int i = 0; i < 4; ++i) {
        const int mloc  = 64 * wy + 16 * i + 4 * g;        // local row base
        const int mbase = m0 + mloc;                       // 4 consecutive rows
        float x2v[4];
        #pragma unroll
        for (int r = 0; r < 4; ++r) x2v[r] = nA[mloc + r];
        float rs[4] = {0.f, 0.f, 0.f, 0.f};
        #pragma unroll
        for (int j = 0; j < 4; ++j) {
            #pragma unroll
            for (int r = 0; r < 4; ++r) {
                float d2 = x2v[r] + c2v[j] - 2.0f * acc[i][j][r];
                d2 = fmaxf(d2, 0.0f);
                rs[r] += wv[j] * __expf(-sigma * d2);
            }
        }
        #pragma unroll
        for (int r = 0; r < 4; ++r) {
            rs[r] += __shfl_xor(rs[r], 1);
            rs[r] += __shfl_xor(rs[r], 2);
            rs[r] += __shfl_xor(rs[r], 4);
            rs[r] += __shfl_xor(rs[r], 8);
        }
        if (lr == 0) {
            #pragma unroll
            for (int r = 0; r < 4; ++r) atomicAdd(&out[mbase + r], rs[r]);
        }
    }
}

extern "C" void kernel_launch(void* const* d_in, const int* in_sizes, int n_in,
                              void* d_out, int out_size, void* d_ws, size_t ws_size,
                              hipStream_t stream) {
    const float* x    = (const float*)d_in[0];
    const float* cent = (const float*)d_in[1];
    const float* w    = (const float*)d_in[2];
    const float* sig  = (const float*)d_in[3];
    float* out = (float*)d_out;

    hipMemsetAsync(d_out, 0, (size_t)out_size * sizeof(float), stream);
    rbf_fused<<<dim3(NCENT / 128, NROWS / 128), 256, 0, stream>>>(x, cent, w, sig, out);
}

// Round 14
// 102.851 us; speedup vs baseline: 1.7590x; 1.7590x over previous
//
#include <hip/hip_runtime.h>

#define NROWS 8192
#define NCENT 4096
#define DIM   256

#define AS1 __attribute__((address_space(1)))
#define AS3 __attribute__((address_space(3)))

typedef short bf16x8 __attribute__((ext_vector_type(8)));
typedef float f32x4  __attribute__((ext_vector_type(4)));

// fp32 -> bf16 round-to-nearest-even
__device__ inline unsigned short f2bf(float f) {
    unsigned u = __float_as_uint(f);
    return (unsigned short)((u + 0x7fffu + ((u >> 16) & 1u)) >> 16);
}

// ---------------------------------------------------------------------------
// Prepass: fp32 -> bf16 convert (row-major, unswizzled) + row norms.
// Also zeroes out[] (blocks 0..31), replacing the separate memset dispatch.
// 4 waves/block, 4 rows/wave -> 16 rows/block, 768 blocks.
// ws layout: norms[12288] | xbf[8192*256] | cbf[4096*256]
// ---------------------------------------------------------------------------
__global__ __launch_bounds__(256) void prep_kernel(const float* __restrict__ x,
                                                   const float* __restrict__ c,
                                                   float* __restrict__ norms,
                                                   unsigned short* __restrict__ xbf,
                                                   unsigned short* __restrict__ cbf,
                                                   float* __restrict__ out) {
    const int t = threadIdx.x, lane = t & 63;
    if (blockIdx.x < NROWS / 256) out[blockIdx.x * 256 + t] = 0.0f;
    const int wbase = (blockIdx.x * 4 + (t >> 6)) * 4;   // first row of this wave
    #pragma unroll
    for (int rr = 0; rr < 4; ++rr) {
        const int gw = wbase + rr;                        // 0..12287
        const float* src;
        unsigned short* dst;
        if (gw < NROWS) { src = x + (size_t)gw * DIM;           dst = xbf + (size_t)gw * DIM; }
        else            { src = c + (size_t)(gw - NROWS) * DIM; dst = cbf + (size_t)(gw - NROWS) * DIM; }
        float4 v = ((const float4*)src)[lane];
        ushort4 b;
        b.x = f2bf(v.x); b.y = f2bf(v.y); b.z = f2bf(v.z); b.w = f2bf(v.w);
        ((ushort4*)dst)[lane] = b;
        float s = v.x * v.x + v.y * v.y + v.z * v.z + v.w * v.w;
        #pragma unroll
        for (int m = 32; m; m >>= 1) s += __shfl_xor(s, m);
        if (lane == 0) norms[gw] = s;
    }
}

// ---------------------------------------------------------------------------
// Main kernel: 128x128 block tile, BK=32, 4 waves in 2x2 wave grid,
// 4x4 MFMA (16x16x32 bf16) tiles per wave. global_load_lds width-16 staging.
// Best-measured configuration of the session (103.3 us total): cross-iter
// double buffer with a SINGLE __syncthreads per K-iter:
//     STAGE(next buf, kt+1)   // issue loads
//     compute(cur buf)        // ds_read + 16 MFMA hides load latency
//     __syncthreads()         // drains vmcnt; WAR+RAW safe
// No inline asm, no setprio, no sched_barrier, no launch-bounds cap — every
// one of those was measured neutral or regressive (R7-R13 ledger).
// LDS logical layout: row-major [row][32 bf16], 64 B/row; chunk (16 B) at
// physical position p holds logical chunk p ^ ((row>>1)&3)  -> frag reads are
// 2-way bank aliasing (free, m136). Swizzle applied via staging SOURCE addr
// (global_load_lds dest is forced lane-contiguous, m104/m108).
// ---------------------------------------------------------------------------
#define BUFH (128 * 32)   // shorts per matrix per buffer (8 KB)

__global__ __launch_bounds__(256) void rbf_mfma(const unsigned short* __restrict__ xbf,
                                                const unsigned short* __restrict__ cbf,
                                                const float* __restrict__ w,
                                                const float* __restrict__ sigp,
                                                const float* __restrict__ norms,
                                                float* __restrict__ out) {
    __shared__ __align__(16) short As[2 * BUFH];   // 16 KB
    __shared__ __align__(16) short Bs[2 * BUFH];   // 16 KB

    const int t    = threadIdx.x;
    const int wave = t >> 6, lane = t & 63;
    const int m0   = blockIdx.y * 128;
    const int n0   = blockIdx.x * 128;
    const int wy   = wave >> 1, wx = wave & 1;
    const int lr   = lane & 15;       // frag m/n index
    const int g    = lane >> 4;       // frag k-group

    // ---- staging: wave stages rows 32w..32w+31 of both tiles (2 issues ea) ----
    const int r_in = lane >> 2;                        // 0..15 within 16-row group
    const int c_l  = (lane & 3) ^ ((r_in >> 1) & 3);   // logical chunk for this lane
    const unsigned short* ga0 = xbf + (size_t)(m0 + 32 * wave + r_in) * DIM + c_l * 8;
    const unsigned short* ga1 = ga0 + 16 * DIM;
    const unsigned short* gb0 = cbf + (size_t)(n0 + 32 * wave + r_in) * DIM + c_l * 8;
    const unsigned short* gb1 = gb0 + 16 * DIM;
    short* la0 = As + (32 * wave) * 32;                // uniform dest base per wave
    short* lb0 = Bs + (32 * wave) * 32;

#define STAGE(buf, kk) do {                                                                  \
        const int ko_ = (kk) * 32;                                                           \
        __builtin_amdgcn_global_load_lds((const AS1 void*)(ga0 + ko_),                       \
                                         (AS3 void*)(la0 + (buf) * BUFH), 16, 0, 0);         \
        __builtin_amdgcn_global_load_lds((const AS1 void*)(ga1 + ko_),                       \
                                         (AS3 void*)(la0 + (buf) * BUFH + 16 * 32), 16, 0, 0);\
        __builtin_amdgcn_global_load_lds((const AS1 void*)(gb0 + ko_),                       \
                                         (AS3 void*)(lb0 + (buf) * BUFH), 16, 0, 0);         \
        __builtin_amdgcn_global_load_lds((const AS1 void*)(gb1 + ko_),                       \
                                         (AS3 void*)(lb0 + (buf) * BUFH + 16 * 32), 16, 0, 0);\
    } while (0)

    // ---- fragment read offsets (shorts) ----
    int aoff[4], boff[4];
    #pragma unroll
    for (int i = 0; i < 4; ++i) {
        int r = 64 * wy + 16 * i + lr;
        aoff[i] = r * 32 + ((g ^ ((r >> 1) & 3)) * 8);
    }
    #pragma unroll
    for (int j = 0; j < 4; ++j) {
        int r = 64 * wx + 16 * j + lr;
        boff[j] = r * 32 + ((g ^ ((r >> 1) & 3)) * 8);
    }

    f32x4 acc[4][4];
    #pragma unroll
    for (int i = 0; i < 4; ++i)
        #pragma unroll
        for (int j = 0; j < 4; ++j) acc[i][j] = f32x4{0, 0, 0, 0};

    // ---- prologue: stage tile 0; single exposed drain ----
    STAGE(0, 0);
    __syncthreads();

    #pragma unroll
    for (int kk = 0; kk < DIM / 32; ++kk) {
        const int cur = kk & 1;
        if (kk < DIM / 32 - 1) STAGE(cur ^ 1, kk + 1);   // issue next; lands under compute

        const short* Ab = As + cur * BUFH;
        const short* Bb = Bs + cur * BUFH;
        bf16x8 a[4], b[4];
        #pragma unroll
        for (int i = 0; i < 4; ++i) a[i] = *(const bf16x8*)(Ab + aoff[i]);
        #pragma unroll
        for (int j = 0; j < 4; ++j) b[j] = *(const bf16x8*)(Bb + boff[j]);
        #pragma unroll
        for (int i = 0; i < 4; ++i)
            #pragma unroll
            for (int j = 0; j < 4; ++j)
                acc[i][j] = __builtin_amdgcn_mfma_f32_16x16x32_bf16(a[i], b[j], acc[i][j], 0, 0, 0);

        __syncthreads();   // drains next-tile loads (hidden by compute); WAR-safe
    }
#undef STAGE

    // ---- epilogue: phi = w*exp(-sigma*max(d2,0)); reduce 64 cols per row ----
    const float sigma = sigp[0];
    const float* x2 = norms;
    const float* c2 = norms + NROWS;

    float c2v[4], wv[4];
    #pragma unroll
    for (int j = 0; j < 4; ++j) {
        int n = n0 + 64 * wx + 16 * j + lr;
        c2v[j] = c2[n];
        wv[j]  = w[n];
    }

    #pragma unroll
    for (int i = 0; i < 4; ++i) {
        const int mbase = m0 + 64 * wy + 16 * i + 4 * g;   // 4 consecutive rows
        float4 x2v = *(const float4*)(x2 + mbase);
        float rs[4] = {0.f, 0.f, 0.f, 0.f};
        #pragma unroll
        for (int j = 0; j < 4; ++j) {
            #pragma unroll
            for (int r = 0; r < 4; ++r) {
                float x2r = (r == 0) ? x2v.x : (r == 1) ? x2v.y : (r == 2) ? x2v.z : x2v.w;
                float d2 = x2r + c2v[j] - 2.0f * acc[i][j][r];
                d2 = fmaxf(d2, 0.0f);
                rs[r] += wv[j] * __expf(-sigma * d2);
            }
        }
        #pragma unroll
        for (int r = 0; r < 4; ++r) {
            rs[r] += __shfl_xor(rs[r], 1);
            rs[r] += __shfl_xor(rs[r], 2);
            rs[r] += __shfl_xor(rs[r], 4);
            rs[r] += __shfl_xor(rs[r], 8);
        }
        if (lr == 0) {
            #pragma unroll
            for (int r = 0; r < 4; ++r) atomicAdd(&out[mbase + r], rs[r]);
        }
    }
}

// ---------------------------------------------------------------------------
// Fallback (R2 kernels) if ws is too small for the bf16 scratch copies.
// ---------------------------------------------------------------------------
__global__ __launch_bounds__(256) void norms_kernel(const float* __restrict__ x,
                                                    const float* __restrict__ c,
                                                    float* __restrict__ ws) {
    int t = threadIdx.x, lane = t & 63;
    int gw = blockIdx.x * 4 + (t >> 6);
    const float* src;
    float* dst;
    if (gw < NROWS) { src = x + (size_t)gw * DIM;           dst = ws + gw; }
    else            { src = c + (size_t)(gw - NROWS) * DIM; dst = ws + gw; }
    float4 v = ((const float4*)src)[lane];
    float s = v.x * v.x + v.y * v.y + v.z * v.z + v.w * v.w;
    #pragma unroll
    for (int m = 32; m; m >>= 1) s += __shfl_xor(s, m);
    if (lane == 0) *dst = s;
}

__global__ __launch_bounds__(256) void rbf_kernel(const float* __restrict__ x,
                                                  const float* __restrict__ cent,
                                                  const float* __restrict__ w,
                                                  const float* __restrict__ sigp,
                                                  const float* __restrict__ norms,
                                                  float* __restrict__ out) {
    __shared__ __align__(16) short xs[64 * 32];
    __shared__ __align__(16) short cs[64 * 32];
    const int t = threadIdx.x;
    const int m0 = blockIdx.y * 64, n0 = blockIdx.x * 64;
    const int srow = t >> 2, seg = t & 3;
    const int pchunk = seg ^ ((srow >> 1) & 3);
    const int sidx = srow * 32 + pchunk * 8;
    const float* xg = x    + (size_t)(m0 + srow) * DIM + seg * 8;
    const float* cg = cent + (size_t)(n0 + srow) * DIM + seg * 8;
    const int lane = t & 63, wave = t >> 6;
    const int lr = lane & 15, lg = lane >> 4;
    const int arow = 16 * wave + lr;
    const int aidx = arow * 32 + ((lg ^ ((arow >> 1) & 3)) * 8);
    f32x4 acc[4] = {f32x4{0,0,0,0}, f32x4{0,0,0,0}, f32x4{0,0,0,0}, f32x4{0,0,0,0}};
    for (int k0 = 0; k0 < DIM; k0 += 32) {
        float4 f0 = *(const float4*)(xg + k0);
        float4 f1 = *(const float4*)(xg + k0 + 4);
        float4 g0 = *(const float4*)(cg + k0);
        float4 g1 = *(const float4*)(cg + k0 + 4);
        __syncthreads();
        union { unsigned short s[8]; int4 v; } ux, uc;
        ux.s[0]=f2bf(f0.x); ux.s[1]=f2bf(f0.y); ux.s[2]=f2bf(f0.z); ux.s[3]=f2bf(f0.w);
        ux.s[4]=f2bf(f1.x); ux.s[5]=f2bf(f1.y); ux.s[6]=f2bf(f1.z); ux.s[7]=f2bf(f1.w);
        uc.s[0]=f2bf(g0.x); uc.s[1]=f2bf(g0.y); uc.s[2]=f2bf(g0.z); uc.s[3]=f2bf(g0.w);
        uc.s[4]=f2bf(g1.x); uc.s[5]=f2bf(g1.y); uc.s[6]=f2bf(g1.z); uc.s[7]=f2bf(g1.w);
        *(int4*)(xs + sidx) = ux.v;
        *(int4*)(cs + sidx) = uc.v;
        __syncthreads();
        bf16x8 a = *(const bf16x8*)(xs + aidx);
        #pragma unroll
        for (int bt = 0; bt < 4; ++bt) {
            const int brow = 16 * bt + lr;
            bf16x8 b = *(const bf16x8*)(cs + brow * 32 + ((lg ^ ((brow >> 1) & 3)) * 8));
            acc[bt] = __builtin_amdgcn_mfma_f32_16x16x32_bf16(a, b, acc[bt], 0, 0, 0);
        }
    }
    const float sigma = sigp[0];
    const float* x2 = norms;
    const float* c2 = norms + NROWS;
    const int rbase = m0 + 16 * wave + lg * 4;
    float x2v[4];
    #pragma unroll
    for (int r = 0; r < 4; ++r) x2v[r] = x2[rbase + r];
    float rs[4] = {0.f, 0.f, 0.f, 0.f};
    #pragma unroll
    for (int bt = 0; bt < 4; ++bt) {
        const int col = n0 + 16 * bt + lr;
        const float c2v = c2[col];
        const float wvv = w[col];
        #pragma unroll
        for (int r = 0; r < 4; ++r) {
            float d2 = x2v[r] + c2v - 2.0f * acc[bt][r];
            d2 = fmaxf(d2, 0.0f);
            rs[r] += wvv * __expf(-sigma * d2);
        }
    }
    #pragma unroll
    for (int r = 0; r < 4; ++r) {
        rs[r] += __shfl_xor(rs[r], 1);
        rs[r] += __shfl_xor(rs[r], 2);
        rs[r] += __shfl_xor(rs[r], 4);
        rs[r] += __shfl_xor(rs[r], 8);
    }
    if (lr == 0) {
        #pragma unroll
        for (int r = 0; r < 4; ++r) atomicAdd(&out[rbase + r], rs[r]);
    }
}

extern "C" void kernel_launch(void* const* d_in, const int* in_sizes, int n_in,
                              void* d_out, int out_size, void* d_ws, size_t ws_size,
                              hipStream_t stream) {
    const float* x    = (const float*)d_in[0];
    const float* cent = (const float*)d_in[1];
    const float* w    = (const float*)d_in[2];
    const float* sig  = (const float*)d_in[3];
    float* out = (float*)d_out;

    const size_t norms_elems = NROWS + NCENT;              // 12288 floats
    const size_t xbf_off  = norms_elems * sizeof(float);   // 48 KB
    const size_t cbf_off  = xbf_off + (size_t)NROWS * DIM * sizeof(unsigned short);
    const size_t ws_need  = cbf_off + (size_t)NCENT * DIM * sizeof(unsigned short);

    if (ws_size >= ws_need) {
        float* norms = (float*)d_ws;
        unsigned short* xbf = (unsigned short*)((char*)d_ws + xbf_off);
        unsigned short* cbf = (unsigned short*)((char*)d_ws + cbf_off);
        prep_kernel<<<(NROWS + NCENT) / 16, 256, 0, stream>>>(x, cent, norms, xbf, cbf, out);
        rbf_mfma<<<dim3(NCENT / 128, NROWS / 128), 256, 0, stream>>>(xbf, cbf, w, sig, norms, out);
    } else {
        float* norms = (float*)d_ws;
        hipMemsetAsync(d_out, 0, (size_t)out_size * sizeof(float), stream);
        norms_kernel<<<(NROWS + NCENT) / 4, 256, 0, stream>>>(x, cent, norms);
        rbf_kernel<<<dim3(NCENT / 64, NROWS / 64), 256, 0, stream>>>(x, cent, w, sig, norms, out);
    }
}